// Round 9
// baseline (67.649 us; speedup 1.0000x reference)
//
#include <hip/hip_runtime.h>
#include <math.h>

// Problem constants
#define BATCH 4096
#define NFEAT 2048
#define NNEUR 1024
#define NTGT  8
#define NNZ1  65536
#define NNZ2  8192

// GEMM: h[m][n] = sigmoid( sum_k W1b[m][k]*xb[n][k] + b1[m] ), fused layer-2
// epilogue (atomicAdd into out). M=1024, N=4096, K=2048.
// 8-phase-style schedule (T3+T4+T5): 128x128 tile, BK=64, 512 thr (8 waves,
// 2m x 4n, wave tile 64x32), 32 K-steps x 16 MFMA/wave, 4 LDS buffers (128KB,
// 1 block/CU), counted vmcnt(8), 2 phases/step with setprio MFMA clusters.
#define BM 128
#define BN 128
#define BK 64
#define KSTEPS (NFEAT / BK)   // 32

typedef short  bf16x8 __attribute__((ext_vector_type(8)));
typedef float  f32x4  __attribute__((ext_vector_type(4)));

// ---------------- workspace layout (bytes) ----------------
#define OFF_W1F  ((size_t)0)
#define OFF_W2D  ((size_t)8388608)
#define OFF_W1B  ((size_t)8421376)
#define OFF_XB   ((size_t)12615680)

#define ZERO_FLOAT4 526336               // W1f+W2d contiguous
#define OUT_FLOAT4  (BATCH * NTGT / 4)   // 8192

__device__ __forceinline__ unsigned short f2bf(float f) {
    union { float f; unsigned int u; } a; a.f = f;
    unsigned int u = a.u;
    u += 0x7fffu + ((u >> 16) & 1u);   // round-to-nearest-even
    return (unsigned short)(u >> 16);
}

__device__ __forceinline__ void load_lds16(const unsigned short* g, unsigned short* l) {
    __builtin_amdgcn_global_load_lds(
        (const __attribute__((address_space(1))) unsigned int*)g,
        (__attribute__((address_space(3))) unsigned int*)l,
        16, 0, 0);
}

// zero W1f+W2d and pre-fill out with b2 (k_gemm atomicAdds into out)
__global__ void k_zero(float4* __restrict__ ws4, float4* __restrict__ out4,
                       const float* __restrict__ b2) {
    int i = blockIdx.x * blockDim.x + threadIdx.x;
    if (i < ZERO_FLOAT4) {
        ws4[i] = make_float4(0.f, 0.f, 0.f, 0.f);
    } else {
        int j = i - ZERO_FLOAT4;
        if (j < OUT_FLOAT4) {
            int p = (j & 1) * 4;
            out4[j] = make_float4(b2[p], b2[p + 1], b2[p + 2], b2[p + 3]);
        }
    }
}

// scatter-add edges into dense W1f and W2d (handles duplicate edges by summing)
__global__ void k_build(const float* __restrict__ w1, const int* __restrict__ c1o,
                        const int* __restrict__ c1i,
                        const float* __restrict__ w2, const int* __restrict__ c2o,
                        const int* __restrict__ c2i,
                        float* __restrict__ W1f, float* __restrict__ W2d) {
    int i = blockIdx.x * blockDim.x + threadIdx.x;
    if (i < NNZ1) {
        atomicAdd(&W1f[(size_t)c1o[i] * NFEAT + c1i[i]], w1[i]);
    } else {
        int j = i - NNZ1;
        if (j < NNZ2) atomicAdd(&W2d[c2i[j] * NTGT + c2o[j]], w2[j]);
    }
}

// convert W1f -> W1b and x -> xb, float4 -> 4x bf16 per thread
__global__ void k_convert(const float* __restrict__ W1f, const float* __restrict__ x,
                          unsigned short* __restrict__ W1b, unsigned short* __restrict__ xb) {
    int i = blockIdx.x * blockDim.x + threadIdx.x;
    const int nW = NNEUR * NFEAT / 4;
    const int nX = BATCH * NFEAT / 4;
    if (i < nW) {
        float4 v = ((const float4*)W1f)[i];
        ushort4 o;
        o.x = f2bf(v.x); o.y = f2bf(v.y); o.z = f2bf(v.z); o.w = f2bf(v.w);
        ((ushort4*)W1b)[i] = o;
    } else if (i < nW + nX) {
        int j = i - nW;
        float4 v = ((const float4*)x)[j];
        ushort4 o;
        o.x = f2bf(v.x); o.y = f2bf(v.y); o.z = f2bf(v.z); o.w = f2bf(v.w);
        ((ushort4*)xb)[j] = o;
    }
}

// bf16 MFMA GEMM, 8-phase-style schedule, fused bias+sigmoid+layer2 epilogue.
__global__ __launch_bounds__(512) void k_gemm(const unsigned short* __restrict__ W1b,
                                              const unsigned short* __restrict__ xb,
                                              const float* __restrict__ b1,
                                              const float* __restrict__ W2d,
                                              float* __restrict__ out) {
    // 4 buffers x (A 128x64 + B 128x64) bf16 = 128 KB total
    __shared__ unsigned short ldsA[4][BM * BK];
    __shared__ unsigned short ldsB[4][BN * BK];

    // bijective XCD swizzle: 256 blocks, each XCD gets 4 n-tiles x 8 m-tiles
    int bid  = blockIdx.x;                 // 0..255
    int virt = (bid & 7) * 32 + (bid >> 3);
    int n0 = (virt >> 3) * BN;             // 32 n-tiles
    int mt = virt & 7;                     // 8 m-tiles
    int m0 = mt * BM;

    int tid  = threadIdx.x;
    int wv   = tid >> 6;
    int lane = tid & 63;
    int wm = wv >> 2, wn = wv & 3;         // wave grid 2m x 4n, wave tile 64x32
    int lr = lane & 15, lg = lane >> 4;

    f32x4 zero4 = {0.f, 0.f, 0.f, 0.f};
    f32x4 acc[4][2];
#pragma unroll
    for (int i = 0; i < 4; ++i)
#pragma unroll
        for (int j = 0; j < 2; ++j) acc[i][j] = zero4;

    // ---- staging: linear LDS dest, pre-swizzled global k-slot (rule #21) ----
    // Tile row = 64 bf16 = 128 B = 8 16B-units. unit u: row=u>>3, slot=u&7.
    // gslot = (u&7) ^ ((u>>3)&7); same formula for u and u+512 (row+64).
    int gslot = ((tid & 7) ^ ((tid >> 3) & 7)) * 8;
    const unsigned short* gA0 = &W1b[(size_t)(m0 +      (tid >> 3)) * NFEAT + gslot];
    const unsigned short* gA1 = &W1b[(size_t)(m0 + 64 + (tid >> 3)) * NFEAT + gslot];
    const unsigned short* gB0 = &xb [(size_t)(n0 +      (tid >> 3)) * NFEAT + gslot];
    const unsigned short* gB1 = &xb [(size_t)(n0 + 64 + (tid >> 3)) * NFEAT + gslot];
    const int base0 = (wv * 64) * 8;          // wave-uniform; lane at +lane*16B
    const int base1 = (512 + wv * 64) * 8;

    // read-side swizzle: unit%8 = (kc*4+lg) ^ (row&7), row&7 == lr&7
    const int xorv = lr & 7;

#define SA(T, BUF) do { int k0 = (T) * BK;                          \
        load_lds16(gA0 + k0, &ldsA[BUF][base0]);                    \
        load_lds16(gA1 + k0, &ldsA[BUF][base1]); } while (0)
#define SB(T, BUF) do { int k0 = (T) * BK;                          \
        load_lds16(gB0 + k0, &ldsB[BUF][base0]);                    \
        load_lds16(gB1 + k0, &ldsB[BUF][base1]); } while (0)

    // one phase: ds_read 6 frags (kslot KC), drain lgkm, setprio-wrapped 8 MFMA
#define PHASE(BUF, KC) do {                                         \
        const unsigned short* bA = ldsA[BUF];                       \
        const unsigned short* bB = ldsB[BUF];                       \
        bf16x8 af[4], bg[2];                                        \
        _Pragma("unroll")                                           \
        for (int i = 0; i < 4; ++i) {                               \
            int row = wm * 64 + i * 16 + lr;                        \
            af[i] = *(const bf16x8*)&bA[row * 64 + ((((KC) << 2) + lg) ^ xorv) * 8]; \
        }                                                           \
        _Pragma("unroll")                                           \
        for (int j = 0; j < 2; ++j) {                               \
            int row = wn * 32 + j * 16 + lr;                        \
            bg[j] = *(const bf16x8*)&bB[row * 64 + ((((KC) << 2) + lg) ^ xorv) * 8]; \
        }                                                           \
        asm volatile("s_waitcnt lgkmcnt(0)" ::: "memory");          \
        __builtin_amdgcn_sched_barrier(0);                          \
        __builtin_amdgcn_s_setprio(1);                              \
        _Pragma("unroll")                                           \
        for (int i = 0; i < 4; ++i)                                 \
            _Pragma("unroll")                                       \
            for (int j = 0; j < 2; ++j)                             \
                acc[i][j] = __builtin_amdgcn_mfma_f32_16x16x32_bf16(af[i], bg[j], acc[i][j], 0, 0, 0); \
        __builtin_amdgcn_s_setprio(0);                              \
        __builtin_amdgcn_sched_barrier(0);                          \
    } while (0)

    // prologue: stage steps 0,1,2 (12 lines in flight)
    SA(0, 0); SB(0, 0);
    SA(1, 1); SB(1, 1);
    SA(2, 2); SB(2, 2);

    // main loop: per step, ONE counted vmcnt + ONE barrier; stage lines of
    // step t+3 interleaved between the two MFMA phases of step t.
    for (int t = 0; t < KSTEPS - 3; ++t) {      // t = 0..28, stages 3..31
        asm volatile("s_waitcnt vmcnt(8)" ::: "memory");   // step t's 4 done
        __builtin_amdgcn_s_barrier();
        SA(t + 3, (t + 3) & 3);
        PHASE(t & 3, 0);
        SB(t + 3, (t + 3) & 3);
        PHASE(t & 3, 1);
    }
    // peeled tail: steps 29, 30, 31 (outstanding 8 -> 4 -> 0)
    asm volatile("s_waitcnt vmcnt(8)" ::: "memory");
    __builtin_amdgcn_s_barrier();
    PHASE(29 & 3, 0); PHASE(29 & 3, 1);
    asm volatile("s_waitcnt vmcnt(4)" ::: "memory");
    __builtin_amdgcn_s_barrier();
    PHASE(30 & 3, 0); PHASE(30 & 3, 1);
    asm volatile("s_waitcnt vmcnt(0)" ::: "memory");
    __builtin_amdgcn_s_barrier();
    PHASE(31 & 3, 0); PHASE(31 & 3, 1);

#undef SA
#undef SB
#undef PHASE

    // ---- fused epilogue: h = sigmoid(acc + b1); pt[j][t] = sum_m h*W2d[m][t]
    // C/D layout: col(n) = lane&15, row(m) = (lane>>4)*4 + reg  [m89-verified]
    float pt[2][NTGT];
#pragma unroll
    for (int j = 0; j < 2; ++j)
#pragma unroll
        for (int t = 0; t < NTGT; ++t) pt[j][t] = 0.f;

#pragma unroll
    for (int i = 0; i < 4; ++i) {
#pragma unroll
        for (int r = 0; r < 4; ++r) {
            int ml = wm * 64 + i * 16 + lg * 4 + r;
            float bn = b1[m0 + ml];
            float4 w2lo = *(const float4*)&W2d[(m0 + ml) * NTGT];
            float4 w2hi = *(const float4*)&W2d[(m0 + ml) * NTGT + 4];
#pragma unroll
            for (int j = 0; j < 2; ++j) {
                float h = 1.f / (1.f + __expf(-(acc[i][j][r] + bn)));
                pt[j][0] += h * w2lo.x; pt[j][1] += h * w2lo.y;
                pt[j][2] += h * w2lo.z; pt[j][3] += h * w2lo.w;
                pt[j][4] += h * w2hi.x; pt[j][5] += h * w2hi.y;
                pt[j][6] += h * w2hi.z; pt[j][7] += h * w2hi.w;
            }
        }
    }
    // reduce over lg (lanes lr+16*lg share the same n column)
#pragma unroll
    for (int j = 0; j < 2; ++j)
#pragma unroll
        for (int t = 0; t < NTGT; ++t) {
            float val = pt[j][t];
            val += __shfl_xor(val, 16, 64);
            val += __shfl_xor(val, 32, 64);
            pt[j][t] = val;
        }

    // s_pt aliases ldsB buffer 0 (free after the main loop)
    float (*s_pt)[BN][NTGT] = (float (*)[BN][NTGT])(&ldsB[0][0]);
    __syncthreads();
    if (lg == 0) {
#pragma unroll
        for (int j = 0; j < 2; ++j) {
            int nl = wn * 32 + j * 16 + lr;
#pragma unroll
            for (int t = 0; t < NTGT; ++t)
                s_pt[wm][nl][t] = pt[j][t];
        }
    }
    __syncthreads();
    // atomic add 128 n x 8 t into out (pre-filled with b2); coalesced by tid
    for (int idx = tid; idx < BN * NTGT; idx += 512) {
        int nl = idx >> 3, t = idx & 7;
        atomicAdd(&out[(size_t)(n0 + nl) * NTGT + t], s_pt[0][nl][t] + s_pt[1][nl][t]);
    }
}

extern "C" void kernel_launch(void* const* d_in, const int* in_sizes, int n_in,
                              void* d_out, int out_size, void* d_ws, size_t ws_size,
                              hipStream_t stream) {
    (void)in_sizes; (void)n_in; (void)out_size; (void)ws_size;
    const float* x   = (const float*)d_in[0];
    const float* w1  = (const float*)d_in[1];
    const float* b1  = (const float*)d_in[2];
    const float* w2  = (const float*)d_in[3];
    const float* b2  = (const float*)d_in[4];
    const int*   c1o = (const int*)d_in[5];
    const int*   c1i = (const int*)d_in[6];
    const int*   c2o = (const int*)d_in[7];
    const int*   c2i = (const int*)d_in[8];
    float* out = (float*)d_out;

    char* ws = (char*)d_ws;
    float*          W1f  = (float*)(ws + OFF_W1F);
    float*          W2d  = (float*)(ws + OFF_W2D);
    unsigned short* W1b  = (unsigned short*)(ws + OFF_W1B);
    unsigned short* xb   = (unsigned short*)(ws + OFF_XB);

    // zero W1f+W2d, pre-fill out with b2
    k_zero<<<(ZERO_FLOAT4 + OUT_FLOAT4 + 255) / 256, 256, 0, stream>>>(
        (float4*)ws, (float4*)out, b2);

    // dense weight build
    k_build<<<(NNZ1 + NNZ2) / 256, 256, 0, stream>>>(w1, c1o, c1i, w2, c2o, c2i, W1f, W2d);

    // fp32 -> bf16 for MFMA operands
    k_convert<<<(NNEUR * NFEAT / 4 + BATCH * NFEAT / 4) / 256, 256, 0, stream>>>(W1f, x, W1b, xb);

    // layer 1 GEMM + bias + sigmoid + layer-2 (atomic) all fused
    k_gemm<<<(NNEUR / BM) * (BATCH / BN), 512, 0, stream>>>(W1b, xb, b1, W2d, out);
}

// Round 10
// 55.597 us; speedup vs baseline: 1.2168x; 1.2168x over previous
//
#include <hip/hip_runtime.h>
#include <math.h>

// Problem constants
#define BATCH 4096
#define NFEAT 2048
#define NNEUR 1024
#define NTGT  8
#define NNZ1  65536
#define NNZ2  8192

// GEMM: h[m][n] = sigmoid( sum_k W1b[m][k]*xb[n][k] + b1[m] ), fused layer-2
// partials. M=1024, N=4096, K=2048.
// REGISTER-STAGED (no global_load_lds): global_load_dwordx4 -> VGPR ->
// ds_write_b128 with XOR-swizzled LDS. 128x64 tile, BK=64 (32 iters),
// 256 thr (4 waves 2m x 2n, wave tile 64x32), grid 512 = 2 blocks/CU.
// Pipeline: loads(t+2) issued before MFMA(t); writes(t+1) right after
// barrier; raw s_barrier (prefetch loads stay in flight across it).
#define BM 128
#define BN 64
#define BK 64
#define KSTEPS (NFEAT / BK)   // 32

typedef short  bf16x8 __attribute__((ext_vector_type(8)));
typedef float  f32x4  __attribute__((ext_vector_type(4)));

// ---------------- workspace layout (bytes) ----------------
#define OFF_W1F  ((size_t)0)
#define OFF_W2D  ((size_t)8388608)
#define OFF_W1B  ((size_t)8421376)
#define OFF_XB   ((size_t)12615680)
#define OFF_PART ((size_t)29392896)

#define ZERO_FLOAT4 526336   // W1f+W2d contiguous

__device__ __forceinline__ unsigned short f2bf(float f) {
    union { float f; unsigned int u; } a; a.f = f;
    unsigned int u = a.u;
    u += 0x7fffu + ((u >> 16) & 1u);   // round-to-nearest-even
    return (unsigned short)(u >> 16);
}

// fast zero of W1f+W2d
__global__ void k_zero4(float4* __restrict__ p) {
    int i = blockIdx.x * blockDim.x + threadIdx.x;
    p[i] = make_float4(0.f, 0.f, 0.f, 0.f);
}

// scatter-add edges into dense W1f and W2d (handles duplicate edges by summing)
__global__ void k_build(const float* __restrict__ w1, const int* __restrict__ c1o,
                        const int* __restrict__ c1i,
                        const float* __restrict__ w2, const int* __restrict__ c2o,
                        const int* __restrict__ c2i,
                        float* __restrict__ W1f, float* __restrict__ W2d) {
    int i = blockIdx.x * blockDim.x + threadIdx.x;
    if (i < NNZ1) {
        atomicAdd(&W1f[(size_t)c1o[i] * NFEAT + c1i[i]], w1[i]);
    } else {
        int j = i - NNZ1;
        if (j < NNZ2) atomicAdd(&W2d[c2i[j] * NTGT + c2o[j]], w2[j]);
    }
}

// convert W1f -> W1b and x -> xb, float4 -> 4x bf16 per thread
__global__ void k_convert(const float* __restrict__ W1f, const float* __restrict__ x,
                          unsigned short* __restrict__ W1b, unsigned short* __restrict__ xb) {
    int i = blockIdx.x * blockDim.x + threadIdx.x;
    const int nW = NNEUR * NFEAT / 4;
    const int nX = BATCH * NFEAT / 4;
    if (i < nW) {
        float4 v = ((const float4*)W1f)[i];
        ushort4 o;
        o.x = f2bf(v.x); o.y = f2bf(v.y); o.z = f2bf(v.z); o.w = f2bf(v.w);
        ((ushort4*)W1b)[i] = o;
    } else if (i < nW + nX) {
        int j = i - nW;
        float4 v = ((const float4*)x)[j];
        ushort4 o;
        o.x = f2bf(v.x); o.y = f2bf(v.y); o.z = f2bf(v.z); o.w = f2bf(v.w);
        ((ushort4*)xb)[j] = o;
    }
}

// bf16 MFMA GEMM, register-staged, fused bias+sigmoid+layer2-partial epilogue.
__global__ __launch_bounds__(256) void k_gemm(const unsigned short* __restrict__ W1b,
                                              const unsigned short* __restrict__ xb,
                                              const float* __restrict__ b1,
                                              const float* __restrict__ W2d,
                                              float* __restrict__ partial) {
    __shared__ unsigned short ldsA[2][BM * BK];   // 2 x 16 KB
    __shared__ unsigned short ldsB[2][BN * BK];   // 2 x 8 KB
    __shared__ float s_w2[BM][NTGT];              // 4 KB
    __shared__ float s_b1[BM];                    // 512 B
    __shared__ float s_pt[2][BN][NTGT];           // 4 KB

    // bijective XCD swizzle: each XCD gets 8 contiguous n-tiles x 8 m-tiles
    int bid = blockIdx.x;                  // 0..511
    int v   = bid >> 3;                    // 0..63
    int n0  = ((bid & 7) * 8 + (v >> 3)) * BN;   // 64 n-tiles
    int mt  = v & 7;                       // 8 m-tiles
    int m0  = mt * BM;

    int tid  = threadIdx.x;
    int wv   = tid >> 6;
    int lane = tid & 63;
    int wm = wv >> 1, wn = wv & 1;         // wave grid 2m x 2n, wave tile 64x32
    int lr = lane & 15, lg = lane >> 4;

    // preload W2d + b1 slices for the epilogue (plain loads; compiler waits)
    for (int i = tid; i < BM * NTGT; i += 256)
        s_w2[i >> 3][i & 7] = W2d[(m0 + (i >> 3)) * NTGT + (i & 7)];
    if (tid < BM) s_b1[tid] = b1[m0 + tid];

    f32x4 zero4 = {0.f, 0.f, 0.f, 0.f};
    f32x4 acc[4][2];
#pragma unroll
    for (int i = 0; i < 4; ++i)
#pragma unroll
        for (int j = 0; j < 2; ++j) acc[i][j] = zero4;

    // ---- reg-staging geometry ----
    // A tile 128x64 bf16 = 1024 16B-units; thread handles units c*256+tid, c<4.
    // B tile  64x64 bf16 =  512 16B-units; c<2. unit u: row=u>>3, slot s=u&7.
    // LDS unit index (XOR swizzle, bank-spread): row*8 + (s ^ (row&7)).
    const unsigned short* gAp[4]; int iwA[4];
#pragma unroll
    for (int c = 0; c < 4; ++c) {
        int u = c * 256 + tid, row = u >> 3, s = u & 7;
        gAp[c] = &W1b[(size_t)(m0 + row) * NFEAT + s * 8];
        iwA[c] = row * 8 + (s ^ (row & 7));
    }
    const unsigned short* gBp[2]; int iwB[2];
#pragma unroll
    for (int c = 0; c < 2; ++c) {
        int u = c * 256 + tid, row = u >> 3, s = u & 7;
        gBp[c] = &xb[(size_t)(n0 + row) * NFEAT + s * 8];
        iwB[c] = row * 8 + (s ^ (row & 7));
    }

    bf16x8 ra0, ra1, ra2, ra3, rb0, rb1;   // staged regs (named; rule #20)

#define LOADR(T) do { int kk = (T) * BK;                            \
        ra0 = *(const bf16x8*)(gAp[0] + kk);                        \
        ra1 = *(const bf16x8*)(gAp[1] + kk);                        \
        ra2 = *(const bf16x8*)(gAp[2] + kk);                        \
        ra3 = *(const bf16x8*)(gAp[3] + kk);                        \
        rb0 = *(const bf16x8*)(gBp[0] + kk);                        \
        rb1 = *(const bf16x8*)(gBp[1] + kk); } while (0)

#define STORE(BUF) do {                                             \
        bf16x8* dA = (bf16x8*)&ldsA[BUF][0];                        \
        bf16x8* dB = (bf16x8*)&ldsB[BUF][0];                        \
        dA[iwA[0]] = ra0; dA[iwA[1]] = ra1;                         \
        dA[iwA[2]] = ra2; dA[iwA[3]] = ra3;                         \
        dB[iwB[0]] = rb0; dB[iwB[1]] = rb1; } while (0)

    bf16x8 af0[4], af1[4], bg0[2], bg1[2];

#define READF(BUF) do {                                             \
        const unsigned short* bA = ldsA[BUF];                       \
        const unsigned short* bB = ldsB[BUF];                       \
        _Pragma("unroll")                                           \
        for (int i = 0; i < 4; ++i) {                               \
            int rowa = wm * 64 + i * 16 + lr;                       \
            af0[i] = *(const bf16x8*)&bA[(rowa * 8 + ((lg)     ^ (rowa & 7))) * 8]; \
            af1[i] = *(const bf16x8*)&bA[(rowa * 8 + ((4 + lg) ^ (rowa & 7))) * 8]; \
        }                                                           \
        _Pragma("unroll")                                           \
        for (int j = 0; j < 2; ++j) {                               \
            int rowb = wn * 32 + j * 16 + lr;                       \
            bg0[j] = *(const bf16x8*)&bB[(rowb * 8 + ((lg)     ^ (rowb & 7))) * 8]; \
            bg1[j] = *(const bf16x8*)&bB[(rowb * 8 + ((4 + lg) ^ (rowb & 7))) * 8]; \
        }                                                           \
    } while (0)

#define MFMAS() do {                                                \
        _Pragma("unroll")                                           \
        for (int i = 0; i < 4; ++i)                                 \
            _Pragma("unroll")                                       \
            for (int j = 0; j < 2; ++j)                             \
                acc[i][j] = __builtin_amdgcn_mfma_f32_16x16x32_bf16(af0[i], bg0[j], acc[i][j], 0, 0, 0); \
        _Pragma("unroll")                                           \
        for (int i = 0; i < 4; ++i)                                 \
            _Pragma("unroll")                                       \
            for (int j = 0; j < 2; ++j)                             \
                acc[i][j] = __builtin_amdgcn_mfma_f32_16x16x32_bf16(af1[i], bg1[j], acc[i][j], 0, 0, 0); \
    } while (0)

    // prologue: tile 0 -> regs -> buf0; tile 1 -> regs (in flight)
    LOADR(0);
    asm volatile("s_waitcnt vmcnt(0)" ::: "memory");
    STORE(0);
    LOADR(1);
    asm volatile("s_waitcnt lgkmcnt(0)" ::: "memory");  // buf0 writes done
    __builtin_amdgcn_s_barrier();

    // main loop. Iter t: buf[t&1] ready; regs hold tile t+1.
    for (int t = 0; t < KSTEPS; ++t) {
        if (t + 1 < KSTEPS) {
            asm volatile("s_waitcnt vmcnt(0)" ::: "memory");  // t+1 regs arrived
            __builtin_amdgcn_sched_barrier(0);
            STORE((t + 1) & 1);            // buf[(t+1)&1] fully read at iter t-1
            if (t + 2 < KSTEPS) LOADR(t + 2);  // in flight across MFMA + barrier
            __builtin_amdgcn_sched_barrier(0);
        }
        READF(t & 1);
        asm volatile("s_waitcnt lgkmcnt(0)" ::: "memory");  // reads + writes done
        __builtin_amdgcn_sched_barrier(0);
        __builtin_amdgcn_s_setprio(1);
        MFMAS();
        __builtin_amdgcn_s_setprio(0);
        __builtin_amdgcn_sched_barrier(0);
        __builtin_amdgcn_s_barrier();      // raw: loads stay in flight
    }

#undef LOADR
#undef STORE
#undef READF
#undef MFMAS

    // ---- fused epilogue: h = sigmoid(acc + b1); pt[j][t] = sum_m h*W2d[m][t]
    // C/D layout: col(n) = lane&15, row(m) = (lane>>4)*4 + reg  [m89-verified]
    float pt[2][NTGT];
#pragma unroll
    for (int j = 0; j < 2; ++j)
#pragma unroll
        for (int t = 0; t < NTGT; ++t) pt[j][t] = 0.f;

#pragma unroll
    for (int i = 0; i < 4; ++i) {
#pragma unroll
        for (int r = 0; r < 4; ++r) {
            int ml = wm * 64 + i * 16 + lg * 4 + r;
            float bn = s_b1[ml];
#pragma unroll
            for (int j = 0; j < 2; ++j) {
                float h = 1.f / (1.f + __expf(-(acc[i][j][r] + bn)));
#pragma unroll
                for (int t = 0; t < NTGT; ++t)
                    pt[j][t] += h * s_w2[ml][t];
            }
        }
    }
    // reduce over lg (lanes lr+16*lg share the same n column)
#pragma unroll
    for (int j = 0; j < 2; ++j)
#pragma unroll
        for (int t = 0; t < NTGT; ++t) {
            float val = pt[j][t];
            val += __shfl_xor(val, 16, 64);
            val += __shfl_xor(val, 32, 64);
            pt[j][t] = val;
        }
    if (lg == 0) {
#pragma unroll
        for (int j = 0; j < 2; ++j) {
            int nl = wn * 32 + j * 16 + lr;
#pragma unroll
            for (int t = 0; t < NTGT; ++t)
                s_pt[wm][nl][t] = pt[j][t];
        }
    }
    __syncthreads();
    // partial[mt][n][t], 64 n x 8 t per block
    for (int idx = tid; idx < BN * NTGT; idx += 256) {
        int nl = idx >> 3, t = idx & 7;
        partial[((size_t)mt * BATCH + (n0 + nl)) * NTGT + t] = s_pt[0][nl][t] + s_pt[1][nl][t];
    }
}

// out[b][t] = b2[t] + sum_mt partial[mt][b][t]
__global__ void k_reduce(const float* __restrict__ partial, const float* __restrict__ b2,
                         float* __restrict__ out) {
    int i = blockIdx.x * blockDim.x + threadIdx.x;  // 32768
    float v = b2[i & 7];
#pragma unroll
    for (int c = 0; c < 8; ++c) v += partial[(size_t)c * BATCH * NTGT + i];
    out[i] = v;
}

extern "C" void kernel_launch(void* const* d_in, const int* in_sizes, int n_in,
                              void* d_out, int out_size, void* d_ws, size_t ws_size,
                              hipStream_t stream) {
    (void)in_sizes; (void)n_in; (void)out_size; (void)ws_size;
    const float* x   = (const float*)d_in[0];
    const float* w1  = (const float*)d_in[1];
    const float* b1  = (const float*)d_in[2];
    const float* w2  = (const float*)d_in[3];
    const float* b2  = (const float*)d_in[4];
    const int*   c1o = (const int*)d_in[5];
    const int*   c1i = (const int*)d_in[6];
    const int*   c2o = (const int*)d_in[7];
    const int*   c2i = (const int*)d_in[8];
    float* out = (float*)d_out;

    char* ws = (char*)d_ws;
    float*          W1f  = (float*)(ws + OFF_W1F);
    float*          W2d  = (float*)(ws + OFF_W2D);
    unsigned short* W1b  = (unsigned short*)(ws + OFF_W1B);
    unsigned short* xb   = (unsigned short*)(ws + OFF_XB);
    float*          part = (float*)(ws + OFF_PART);

    // zero W1f + W2d
    k_zero4<<<ZERO_FLOAT4 / 256, 256, 0, stream>>>((float4*)ws);

    // dense weight build
    k_build<<<(NNZ1 + NNZ2) / 256, 256, 0, stream>>>(w1, c1o, c1i, w2, c2o, c2i, W1f, W2d);

    // fp32 -> bf16 for MFMA operands
    k_convert<<<(NNEUR * NFEAT / 4 + BATCH * NFEAT / 4) / 256, 256, 0, stream>>>(W1f, x, W1b, xb);

    // layer 1 GEMM + bias + sigmoid + layer-2 partials, all fused (reg-staged)
    k_gemm<<<(NNEUR / BM) * (BATCH / BN), 256, 0, stream>>>(W1b, xb, b1, W2d, part);

    // final reduce over the 8 m-tiles
    k_reduce<<<BATCH * NTGT / 256, 256, 0, stream>>>(part, b2, out);
}

// Round 11
// 53.328 us; speedup vs baseline: 1.2686x; 1.0425x over previous
//
#include <hip/hip_runtime.h>
#include <math.h>

// Problem constants
#define BATCH 4096
#define NFEAT 2048
#define NNEUR 1024
#define NTGT  8
#define NNZ1  65536
#define NNZ2  8192

// GEMM: h[m][n] = sigmoid( sum_k W1b[m][k]*xbf(n,k) + b1[m] ), fused layer-2
// partials. M=1024, N=4096, K=2048.
// Register-staged, 2-tiles-in-flight counted-vmcnt pipeline:
//   loads(t+2) issued before MFMA(t); vmcnt(8) waits only the older set.
// B operand read as f32 directly from x, cvt to bf16 in-register at store
// (v_cvt_pk_bf16_f32, RNE == f2bf) -- xb buffer and its 48MB traffic removed.
// 128x64 tile, BK=64 (32 steps), 256 thr (4 waves 2m x 2n, wave 64x32),
// grid 512 = 2 blocks/CU, 2 waves/SIMD.
#define BM 128
#define BN 64
#define BK 64
#define KSTEPS (NFEAT / BK)   // 32

typedef short  bf16x8 __attribute__((ext_vector_type(8)));
typedef float  f32x4  __attribute__((ext_vector_type(4)));

// ---------------- workspace layout (bytes) ----------------
#define OFF_W1F  ((size_t)0)
#define OFF_W2D  ((size_t)8388608)
#define OFF_W1B  ((size_t)8421376)
#define OFF_PART ((size_t)29392896)

#define ZERO_FLOAT4 526336   // W1f+W2d contiguous

__device__ __forceinline__ unsigned short f2bf(float f) {
    union { float f; unsigned int u; } a; a.f = f;
    unsigned int u = a.u;
    u += 0x7fffu + ((u >> 16) & 1u);   // round-to-nearest-even
    return (unsigned short)(u >> 16);
}

// 8x f32 -> 8x bf16 (RNE) packed in uint4, via v_cvt_pk_bf16_f32
__device__ __forceinline__ uint4 pk8(float4 lo, float4 hi) {
    uint4 r;
    asm("v_cvt_pk_bf16_f32 %0, %1, %2" : "=v"(r.x) : "v"(lo.x), "v"(lo.y));
    asm("v_cvt_pk_bf16_f32 %0, %1, %2" : "=v"(r.y) : "v"(lo.z), "v"(lo.w));
    asm("v_cvt_pk_bf16_f32 %0, %1, %2" : "=v"(r.z) : "v"(hi.x), "v"(hi.y));
    asm("v_cvt_pk_bf16_f32 %0, %1, %2" : "=v"(r.w) : "v"(hi.z), "v"(hi.w));
    return r;
}

// fast zero of W1f+W2d
__global__ void k_zero4(float4* __restrict__ p) {
    int i = blockIdx.x * blockDim.x + threadIdx.x;
    p[i] = make_float4(0.f, 0.f, 0.f, 0.f);
}

// scatter-add edges into dense W1f and W2d (handles duplicate edges by summing)
__global__ void k_build(const float* __restrict__ w1, const int* __restrict__ c1o,
                        const int* __restrict__ c1i,
                        const float* __restrict__ w2, const int* __restrict__ c2o,
                        const int* __restrict__ c2i,
                        float* __restrict__ W1f, float* __restrict__ W2d) {
    int i = blockIdx.x * blockDim.x + threadIdx.x;
    if (i < NNZ1) {
        atomicAdd(&W1f[(size_t)c1o[i] * NFEAT + c1i[i]], w1[i]);
    } else {
        int j = i - NNZ1;
        if (j < NNZ2) atomicAdd(&W2d[c2i[j] * NTGT + c2o[j]], w2[j]);
    }
}

// convert W1f -> W1b only (x is consumed as f32 by k_gemm now)
__global__ void k_convert(const float* __restrict__ W1f, unsigned short* __restrict__ W1b) {
    int i = blockIdx.x * blockDim.x + threadIdx.x;   // < NNEUR*NFEAT/4
    float4 v = ((const float4*)W1f)[i];
    ushort4 o;
    o.x = f2bf(v.x); o.y = f2bf(v.y); o.z = f2bf(v.z); o.w = f2bf(v.w);
    ((ushort4*)W1b)[i] = o;
}

// bf16 MFMA GEMM, reg-staged 2-deep pipeline, fused bias+sigmoid+layer2 epilogue.
__global__ __launch_bounds__(256) void k_gemm(const unsigned short* __restrict__ W1b,
                                              const float* __restrict__ x,
                                              const float* __restrict__ b1,
                                              const float* __restrict__ W2d,
                                              float* __restrict__ partial) {
    __shared__ unsigned short ldsA[2][BM * BK];   // 2 x 16 KB
    __shared__ unsigned short ldsB[2][BN * BK];   // 2 x 8 KB
    __shared__ float s_w2[BM][NTGT];              // 4 KB
    __shared__ float s_b1[BM];                    // 512 B
    __shared__ float s_pt[2][BN][NTGT];           // 4 KB

    // bijective XCD swizzle: each XCD gets 8 contiguous n-tiles x 8 m-tiles
    int bid = blockIdx.x;                  // 0..511
    int v   = bid >> 3;                    // 0..63
    int n0  = ((bid & 7) * 8 + (v >> 3)) * BN;   // 64 n-tiles
    int mt  = v & 7;                       // 8 m-tiles
    int m0  = mt * BM;

    int tid  = threadIdx.x;
    int wv   = tid >> 6;
    int lane = tid & 63;
    int wm = wv >> 1, wn = wv & 1;         // wave grid 2m x 2n, wave tile 64x32
    int lr = lane & 15, lg = lane >> 4;

    // preload W2d + b1 slices for the epilogue, then drain so vmcnt counting
    // in the pipeline is exact
    for (int i = tid; i < BM * NTGT; i += 256)
        s_w2[i >> 3][i & 7] = W2d[(m0 + (i >> 3)) * NTGT + (i & 7)];
    if (tid < BM) s_b1[tid] = b1[m0 + tid];
    asm volatile("s_waitcnt vmcnt(0) lgkmcnt(0)" ::: "memory");
    __builtin_amdgcn_sched_barrier(0);

    f32x4 zero4 = {0.f, 0.f, 0.f, 0.f};
    f32x4 acc[4][2];
#pragma unroll
    for (int i = 0; i < 4; ++i)
#pragma unroll
        for (int j = 0; j < 2; ++j) acc[i][j] = zero4;

    // ---- reg-staging geometry ----
    // A tile 128x64 bf16: unit u = c*256+tid (c<4): row = c*32 + (tid>>3),
    //   slot s = tid&7 (k = s*8..s*8+7). LDS unit = row*8 + (s ^ (row&7)).
    // B tile 64x64 f32 -> bf16: pair j = c*256+tid (c<2): row = c*32+(tid>>3),
    //   ps = tid&7 (k = ps*8..ps*8+7, two float4 loads). Same LDS mapping.
    int r0 = tid >> 3, s0 = tid & 7;
    const unsigned short* gA0 = &W1b[(size_t)(m0 + r0) * NFEAT + s0 * 8];
    const unsigned short* gA1 = gA0 + 32 * NFEAT;
    const unsigned short* gA2 = gA0 + 64 * NFEAT;
    const unsigned short* gA3 = gA0 + 96 * NFEAT;
    const float* gB0 = &x[(size_t)(n0 + r0) * NFEAT + s0 * 8];
    const float* gB1 = gB0 + 32 * NFEAT;
    const int iw0 = r0 * 8 + (s0 ^ (r0 & 7));   // row-base 0 mod 8 => same XOR
    const int iw1 = iw0 + 256, iw2 = iw0 + 512, iw3 = iw0 + 768;

    // two named register sets (rule #20: no runtime-indexed arrays)
    bf16x8 A0a, A0b, A0c, A0d;  float4 B0a, B0b, B0c, B0d;
    bf16x8 A1a, A1b, A1c, A1d;  float4 B1a, B1b, B1c, B1d;
    bf16x8 af0[4], af1[4], bg0[2], bg1[2];

#define LOADS0(T) do { int kk = (T) * BK;                           \
        A0a = *(const bf16x8*)(gA0 + kk); A0b = *(const bf16x8*)(gA1 + kk); \
        A0c = *(const bf16x8*)(gA2 + kk); A0d = *(const bf16x8*)(gA3 + kk); \
        B0a = *(const float4*)(gB0 + kk); B0b = *(const float4*)(gB0 + kk + 4); \
        B0c = *(const float4*)(gB1 + kk); B0d = *(const float4*)(gB1 + kk + 4); } while (0)
#define LOADS1(T) do { int kk = (T) * BK;                           \
        A1a = *(const bf16x8*)(gA0 + kk); A1b = *(const bf16x8*)(gA1 + kk); \
        A1c = *(const bf16x8*)(gA2 + kk); A1d = *(const bf16x8*)(gA3 + kk); \
        B1a = *(const float4*)(gB0 + kk); B1b = *(const float4*)(gB0 + kk + 4); \
        B1c = *(const float4*)(gB1 + kk); B1d = *(const float4*)(gB1 + kk + 4); } while (0)

#define STORE0(BUF) do {                                            \
        bf16x8* dA = (bf16x8*)&ldsA[BUF][0];                        \
        dA[iw0] = A0a; dA[iw1] = A0b; dA[iw2] = A0c; dA[iw3] = A0d; \
        uint4* dB = (uint4*)&ldsB[BUF][0];                          \
        dB[iw0] = pk8(B0a, B0b); dB[iw1] = pk8(B0c, B0d); } while (0)
#define STORE1(BUF) do {                                            \
        bf16x8* dA = (bf16x8*)&ldsA[BUF][0];                        \
        dA[iw0] = A1a; dA[iw1] = A1b; dA[iw2] = A1c; dA[iw3] = A1d; \
        uint4* dB = (uint4*)&ldsB[BUF][0];                          \
        dB[iw0] = pk8(B1a, B1b); dB[iw1] = pk8(B1c, B1d); } while (0)

#define READF(BUF) do {                                             \
        const unsigned short* bA = ldsA[BUF];                       \
        const unsigned short* bB = ldsB[BUF];                       \
        _Pragma("unroll")                                           \
        for (int i = 0; i < 4; ++i) {                               \
            int rowa = wm * 64 + i * 16 + lr;                       \
            af0[i] = *(const bf16x8*)&bA[(rowa * 8 + ((lg)     ^ (rowa & 7))) * 8]; \
            af1[i] = *(const bf16x8*)&bA[(rowa * 8 + ((4 + lg) ^ (rowa & 7))) * 8]; \
        }                                                           \
        _Pragma("unroll")                                           \
        for (int j = 0; j < 2; ++j) {                               \
            int rowb = wn * 32 + j * 16 + lr;                       \
            bg0[j] = *(const bf16x8*)&bB[(rowb * 8 + ((lg)     ^ (rowb & 7))) * 8]; \
            bg1[j] = *(const bf16x8*)&bB[(rowb * 8 + ((4 + lg) ^ (rowb & 7))) * 8]; \
        }                                                           \
    } while (0)

#define MFMAS() do {                                                \
        _Pragma("unroll")                                           \
        for (int i = 0; i < 4; ++i)                                 \
            _Pragma("unroll")                                       \
            for (int j = 0; j < 2; ++j)                             \
                acc[i][j] = __builtin_amdgcn_mfma_f32_16x16x32_bf16(af0[i], bg0[j], acc[i][j], 0, 0, 0); \
        _Pragma("unroll")                                           \
        for (int i = 0; i < 4; ++i)                                 \
            _Pragma("unroll")                                       \
            for (int j = 0; j < 2; ++j)                             \
                acc[i][j] = __builtin_amdgcn_mfma_f32_16x16x32_bf16(af1[i], bg1[j], acc[i][j], 0, 0, 0); \
    } while (0)

#define WAIT_VM(N)  asm volatile("s_waitcnt vmcnt(" #N ")" ::: "memory"); \
                    __builtin_amdgcn_sched_barrier(0)
#define WAIT_LGKM() asm volatile("s_waitcnt lgkmcnt(0)" ::: "memory");    \
                    __builtin_amdgcn_sched_barrier(0)

    // prologue: tiles 0,1 -> regs; store tile 0 (set1's 8 loads stay in flight)
    LOADS0(0);
    LOADS1(1);
    WAIT_VM(8);
    STORE0(0);
    WAIT_LGKM();
    __builtin_amdgcn_s_barrier();

    // steady state, unrolled x2. Invariant at even half (tile t):
    //   buf0 = tile t (ready); set1 = t+1 (in flight); set0 free.
#pragma unroll 1
    for (int t = 0; t < KSTEPS - 2; t += 2) {
        // even: compute t, load t+2 -> set0, store t+1 -> buf1
        LOADS0(t + 2);
        __builtin_amdgcn_sched_barrier(0);
        READF(0);
        WAIT_LGKM();
        __builtin_amdgcn_s_setprio(1); MFMAS(); __builtin_amdgcn_s_setprio(0);
        __builtin_amdgcn_sched_barrier(0);
        WAIT_VM(8);                      // set1 (t+1) arrived; set0 still flying
        STORE1(1);
        WAIT_LGKM();
        __builtin_amdgcn_s_barrier();
        // odd: compute t+1, load t+3 -> set1, store t+2 -> buf0
        LOADS1(t + 3);
        __builtin_amdgcn_sched_barrier(0);
        READF(1);
        WAIT_LGKM();
        __builtin_amdgcn_s_setprio(1); MFMAS(); __builtin_amdgcn_s_setprio(0);
        __builtin_amdgcn_sched_barrier(0);
        WAIT_VM(8);                      // set0 (t+2) arrived; set1 still flying
        STORE0(0);
        WAIT_LGKM();
        __builtin_amdgcn_s_barrier();
    }
    // tail: tile 30 in buf0, set1 = tile 31 in flight
    READF(0);
    WAIT_LGKM();
    __builtin_amdgcn_s_setprio(1); MFMAS(); __builtin_amdgcn_s_setprio(0);
    __builtin_amdgcn_sched_barrier(0);
    WAIT_VM(0);                          // set1 (31) arrived
    STORE1(1);
    WAIT_LGKM();
    __builtin_amdgcn_s_barrier();
    READF(1);
    WAIT_LGKM();
    __builtin_amdgcn_s_setprio(1); MFMAS(); __builtin_amdgcn_s_setprio(0);
    __builtin_amdgcn_sched_barrier(0);

#undef LOADS0
#undef LOADS1
#undef STORE0
#undef STORE1
#undef READF
#undef MFMAS
#undef WAIT_VM
#undef WAIT_LGKM

    // ---- fused epilogue: h = sigmoid(acc + b1); pt[j][t] = sum_m h*W2d[m][t]
    // C/D layout: col(n) = lane&15, row(m) = (lane>>4)*4 + reg  [m89-verified]
    float pt[2][NTGT];
#pragma unroll
    for (int j = 0; j < 2; ++j)
#pragma unroll
        for (int t = 0; t < NTGT; ++t) pt[j][t] = 0.f;

#pragma unroll
    for (int i = 0; i < 4; ++i) {
#pragma unroll
        for (int r = 0; r < 4; ++r) {
            int ml = wm * 64 + i * 16 + lg * 4 + r;
            float bn = s_b1[ml];
#pragma unroll
            for (int j = 0; j < 2; ++j) {
                float h = 1.f / (1.f + __expf(-(acc[i][j][r] + bn)));
#pragma unroll
                for (int t = 0; t < NTGT; ++t)
                    pt[j][t] += h * s_w2[ml][t];
            }
        }
    }
    // reduce over lg (lanes lr+16*lg share the same n column)
#pragma unroll
    for (int j = 0; j < 2; ++j)
#pragma unroll
        for (int t = 0; t < NTGT; ++t) {
            float val = pt[j][t];
            val += __shfl_xor(val, 16, 64);
            val += __shfl_xor(val, 32, 64);
            pt[j][t] = val;
        }
    if (lg == 0) {
#pragma unroll
        for (int j = 0; j < 2; ++j) {
            int nl = wn * 32 + j * 16 + lr;
#pragma unroll
            for (int t = 0; t < NTGT; ++t)
                s_pt[wm][nl][t] = pt[j][t];
        }
    }
    __syncthreads();
    // partial[mt][n][t], 64 n x 8 t per block
    for (int idx = tid; idx < BN * NTGT; idx += 256) {
        int nl = idx >> 3, t = idx & 7;
        partial[((size_t)mt * BATCH + (n0 + nl)) * NTGT + t] = s_pt[0][nl][t] + s_pt[1][nl][t];
    }
}

// out[b][t] = b2[t] + sum_mt partial[mt][b][t]
__global__ void k_reduce(const float* __restrict__ partial, const float* __restrict__ b2,
                         float* __restrict__ out) {
    int i = blockIdx.x * blockDim.x + threadIdx.x;  // 32768
    float v = b2[i & 7];
#pragma unroll
    for (int c = 0; c < 8; ++c) v += partial[(size_t)c * BATCH * NTGT + i];
    out[i] = v;
}

extern "C" void kernel_launch(void* const* d_in, const int* in_sizes, int n_in,
                              void* d_out, int out_size, void* d_ws, size_t ws_size,
                              hipStream_t stream) {
    (void)in_sizes; (void)n_in; (void)out_size; (void)ws_size;
    const float* x   = (const float*)d_in[0];
    const float* w1  = (const float*)d_in[1];
    const float* b1  = (const float*)d_in[2];
    const float* w2  = (const float*)d_in[3];
    const float* b2  = (const float*)d_in[4];
    const int*   c1o = (const int*)d_in[5];
    const int*   c1i = (const int*)d_in[6];
    const int*   c2o = (const int*)d_in[7];
    const int*   c2i = (const int*)d_in[8];
    float* out = (float*)d_out;

    char* ws = (char*)d_ws;
    float*          W1f  = (float*)(ws + OFF_W1F);
    float*          W2d  = (float*)(ws + OFF_W2D);
    unsigned short* W1b  = (unsigned short*)(ws + OFF_W1B);
    float*          part = (float*)(ws + OFF_PART);

    // zero W1f + W2d
    k_zero4<<<ZERO_FLOAT4 / 256, 256, 0, stream>>>((float4*)ws);

    // dense weight build
    k_build<<<(NNZ1 + NNZ2) / 256, 256, 0, stream>>>(w1, c1o, c1i, w2, c2o, c2i, W1f, W2d);

    // fp32 -> bf16 for W1 only (x converted in-register inside k_gemm)
    k_convert<<<NNEUR * NFEAT / 4 / 256, 256, 0, stream>>>(W1f, W1b);

    // layer 1 GEMM + bias + sigmoid + layer-2 partials, all fused (reg-staged)
    k_gemm<<<(NNEUR / BM) * (BATCH / BN), 256, 0, stream>>>(W1b, x, b1, W2d, part);

    // final reduce over the 8 m-tiles
    k_reduce<<<BATCH * NTGT / 256, 256, 0, stream>>>(part, b2, out);
}

// Round 12
// 50.202 us; speedup vs baseline: 1.3475x; 1.0623x over previous
//
#include <hip/hip_runtime.h>
#include <math.h>

// Problem constants
#define BATCH 4096
#define NFEAT 2048
#define NNEUR 1024
#define NTGT  8
#define NNZ1  65536
#define NNZ2  8192

// GEMM: h[m][n] = sigmoid( sum_k W1b[m][k]*xbf(n,k) + b1[m] ), fused layer-2
// epilogue (atomicAdd into b2-prefilled out). M=1024, N=4096, K=2048.
// Register-staged, 2-tiles-in-flight pipeline with COMPILER-COUNTED waits:
// no sched_barrier, no setprio, no manual vmcnt (R11 post-mortem: pinning
// the schedule cost ~6us; m141/m190). Only manual asm: lgkmcnt(0) before
// each raw s_barrier (cross-wave LDS visibility).
// B read as f32 from x, cvt to bf16 in-register at LDS store (v_cvt_pk_bf16_f32).
// 128x64 tile, BK=64 (32 steps), 256 thr (4 waves 2m x 2n, wave 64x32),
// grid 512 = 2 blocks/CU.
#define BM 128
#define BN 64
#define BK 64
#define KSTEPS (NFEAT / BK)   // 32

typedef short  bf16x8 __attribute__((ext_vector_type(8)));
typedef float  f32x4  __attribute__((ext_vector_type(4)));

// ---------------- workspace layout (bytes) ----------------
#define OFF_W1F  ((size_t)0)
#define OFF_W2D  ((size_t)8388608)
#define OFF_W1B  ((size_t)8421376)

#define ZERO_FLOAT4 526336               // W1f+W2d contiguous
#define OUT_FLOAT4  (BATCH * NTGT / 4)   // 8192

__device__ __forceinline__ unsigned short f2bf(float f) {
    union { float f; unsigned int u; } a; a.f = f;
    unsigned int u = a.u;
    u += 0x7fffu + ((u >> 16) & 1u);   // round-to-nearest-even
    return (unsigned short)(u >> 16);
}

// 8x f32 -> 8x bf16 (RNE) packed in uint4, via v_cvt_pk_bf16_f32
__device__ __forceinline__ uint4 pk8(float4 lo, float4 hi) {
    uint4 r;
    asm("v_cvt_pk_bf16_f32 %0, %1, %2" : "=v"(r.x) : "v"(lo.x), "v"(lo.y));
    asm("v_cvt_pk_bf16_f32 %0, %1, %2" : "=v"(r.y) : "v"(lo.z), "v"(lo.w));
    asm("v_cvt_pk_bf16_f32 %0, %1, %2" : "=v"(r.z) : "v"(hi.x), "v"(hi.y));
    asm("v_cvt_pk_bf16_f32 %0, %1, %2" : "=v"(r.w) : "v"(hi.z), "v"(hi.w));
    return r;
}

// zero W1f+W2d and pre-fill out with b2 (k_gemm atomicAdds into out)
__global__ void k_zero(float4* __restrict__ ws4, float4* __restrict__ out4,
                       const float* __restrict__ b2) {
    int i = blockIdx.x * blockDim.x + threadIdx.x;
    if (i < ZERO_FLOAT4) {
        ws4[i] = make_float4(0.f, 0.f, 0.f, 0.f);
    } else {
        int j = i - ZERO_FLOAT4;
        if (j < OUT_FLOAT4) {
            int p = (j & 1) * 4;
            out4[j] = make_float4(b2[p], b2[p + 1], b2[p + 2], b2[p + 3]);
        }
    }
}

// scatter-add edges into dense W1f and W2d (handles duplicate edges by summing)
__global__ void k_build(const float* __restrict__ w1, const int* __restrict__ c1o,
                        const int* __restrict__ c1i,
                        const float* __restrict__ w2, const int* __restrict__ c2o,
                        const int* __restrict__ c2i,
                        float* __restrict__ W1f, float* __restrict__ W2d) {
    int i = blockIdx.x * blockDim.x + threadIdx.x;
    if (i < NNZ1) {
        atomicAdd(&W1f[(size_t)c1o[i] * NFEAT + c1i[i]], w1[i]);
    } else {
        int j = i - NNZ1;
        if (j < NNZ2) atomicAdd(&W2d[c2i[j] * NTGT + c2o[j]], w2[j]);
    }
}

// convert W1f -> W1b only (x is consumed as f32 by k_gemm)
__global__ void k_convert(const float* __restrict__ W1f, unsigned short* __restrict__ W1b) {
    int i = blockIdx.x * blockDim.x + threadIdx.x;   // < NNEUR*NFEAT/4
    float4 v = ((const float4*)W1f)[i];
    ushort4 o;
    o.x = f2bf(v.x); o.y = f2bf(v.y); o.z = f2bf(v.z); o.w = f2bf(v.w);
    ((ushort4*)W1b)[i] = o;
}

// bf16 MFMA GEMM, reg-staged 2-deep compiler-scheduled pipeline,
// fused bias+sigmoid+layer2 epilogue (atomic into out).
__global__ __launch_bounds__(256) void k_gemm(const unsigned short* __restrict__ W1b,
                                              const float* __restrict__ x,
                                              const float* __restrict__ b1,
                                              const float* __restrict__ W2d,
                                              float* __restrict__ out) {
    __shared__ unsigned short ldsA[2][BM * BK];   // 2 x 16 KB
    __shared__ unsigned short ldsB[2][BN * BK];   // 2 x 8 KB
    __shared__ float s_w2[BM][NTGT];              // 4 KB
    __shared__ float s_b1[BM];                    // 512 B
    __shared__ float s_pt[2][BN][NTGT];           // 4 KB

    // bijective XCD swizzle: each XCD gets 8 contiguous n-tiles x 8 m-tiles
    int bid = blockIdx.x;                  // 0..511
    int v   = bid >> 3;                    // 0..63
    int n0  = ((bid & 7) * 8 + (v >> 3)) * BN;   // 64 n-tiles
    int mt  = v & 7;                       // 8 m-tiles
    int m0  = mt * BM;

    int tid  = threadIdx.x;
    int wv   = tid >> 6;
    int lane = tid & 63;
    int wm = wv >> 1, wn = wv & 1;         // wave grid 2m x 2n, wave tile 64x32
    int lr = lane & 15, lg = lane >> 4;

    // preload W2d + b1 slices for the epilogue (compiler orders via dataflow)
    for (int i = tid; i < BM * NTGT; i += 256)
        s_w2[i >> 3][i & 7] = W2d[(m0 + (i >> 3)) * NTGT + (i & 7)];
    if (tid < BM) s_b1[tid] = b1[m0 + tid];

    f32x4 zero4 = {0.f, 0.f, 0.f, 0.f};
    f32x4 acc[4][2];
#pragma unroll
    for (int i = 0; i < 4; ++i)
#pragma unroll
        for (int j = 0; j < 2; ++j) acc[i][j] = zero4;

    // ---- reg-staging geometry ----
    // A tile 128x64 bf16: unit u = c*256+tid (c<4): row = c*32 + (tid>>3),
    //   slot s = tid&7. LDS 16B-unit = row*8 + (s ^ (row&7)) (XOR swizzle).
    // B tile 64x64 (f32 -> bf16): same mapping, c<2, two float4 loads per unit.
    int r0 = tid >> 3, s0 = tid & 7;
    const unsigned short* gA0 = &W1b[(size_t)(m0 + r0) * NFEAT + s0 * 8];
    const unsigned short* gA1 = gA0 + 32 * NFEAT;
    const unsigned short* gA2 = gA0 + 64 * NFEAT;
    const unsigned short* gA3 = gA0 + 96 * NFEAT;
    const float* gB0 = &x[(size_t)(n0 + r0) * NFEAT + s0 * 8];
    const float* gB1 = gB0 + 32 * NFEAT;
    const int iw0 = r0 * 8 + (s0 ^ (r0 & 7));
    const int iw1 = iw0 + 256, iw2 = iw0 + 512, iw3 = iw0 + 768;

    // two named register sets (rule #20: no runtime-indexed arrays)
    bf16x8 A0a, A0b, A0c, A0d;  float4 B0a, B0b, B0c, B0d;
    bf16x8 A1a, A1b, A1c, A1d;  float4 B1a, B1b, B1c, B1d;
    bf16x8 af0[4], af1[4], bg0[2], bg1[2];

#define LOADS0(T) do { int kk = (T) * BK;                           \
        A0a = *(const bf16x8*)(gA0 + kk); A0b = *(const bf16x8*)(gA1 + kk); \
        A0c = *(const bf16x8*)(gA2 + kk); A0d = *(const bf16x8*)(gA3 + kk); \
        B0a = *(const float4*)(gB0 + kk); B0b = *(const float4*)(gB0 + kk + 4); \
        B0c = *(const float4*)(gB1 + kk); B0d = *(const float4*)(gB1 + kk + 4); } while (0)
#define LOADS1(T) do { int kk = (T) * BK;                           \
        A1a = *(const bf16x8*)(gA0 + kk); A1b = *(const bf16x8*)(gA1 + kk); \
        A1c = *(const bf16x8*)(gA2 + kk); A1d = *(const bf16x8*)(gA3 + kk); \
        B1a = *(const float4*)(gB0 + kk); B1b = *(const float4*)(gB0 + kk + 4); \
        B1c = *(const float4*)(gB1 + kk); B1d = *(const float4*)(gB1 + kk + 4); } while (0)

#define STORE0(BUF) do {                                            \
        bf16x8* dA = (bf16x8*)&ldsA[BUF][0];                        \
        dA[iw0] = A0a; dA[iw1] = A0b; dA[iw2] = A0c; dA[iw3] = A0d; \
        uint4* dB = (uint4*)&ldsB[BUF][0];                          \
        dB[iw0] = pk8(B0a, B0b); dB[iw1] = pk8(B0c, B0d); } while (0)
#define STORE1(BUF) do {                                            \
        bf16x8* dA = (bf16x8*)&ldsA[BUF][0];                        \
        dA[iw0] = A1a; dA[iw1] = A1b; dA[iw2] = A1c; dA[iw3] = A1d; \
        uint4* dB = (uint4*)&ldsB[BUF][0];                          \
        dB[iw0] = pk8(B1a, B1b); dB[iw1] = pk8(B1c, B1d); } while (0)

#define READF(BUF) do {                                             \
        const unsigned short* bA = ldsA[BUF];                       \
        const unsigned short* bB = ldsB[BUF];                       \
        _Pragma("unroll")                                           \
        for (int i = 0; i < 4; ++i) {                               \
            int rowa = wm * 64 + i * 16 + lr;                       \
            af0[i] = *(const bf16x8*)&bA[(rowa * 8 + ((lg)     ^ (rowa & 7))) * 8]; \
            af1[i] = *(const bf16x8*)&bA[(rowa * 8 + ((4 + lg) ^ (rowa & 7))) * 8]; \
        }                                                           \
        _Pragma("unroll")                                           \
        for (int j = 0; j < 2; ++j) {                               \
            int rowb = wn * 32 + j * 16 + lr;                       \
            bg0[j] = *(const bf16x8*)&bB[(rowb * 8 + ((lg)     ^ (rowb & 7))) * 8]; \
            bg1[j] = *(const bf16x8*)&bB[(rowb * 8 + ((4 + lg) ^ (rowb & 7))) * 8]; \
        }                                                           \
    } while (0)

#define MFMAS() do {                                                \
        _Pragma("unroll")                                           \
        for (int i = 0; i < 4; ++i)                                 \
            _Pragma("unroll")                                       \
            for (int j = 0; j < 2; ++j)                             \
                acc[i][j] = __builtin_amdgcn_mfma_f32_16x16x32_bf16(af0[i], bg0[j], acc[i][j], 0, 0, 0); \
        _Pragma("unroll")                                           \
        for (int i = 0; i < 4; ++i)                                 \
            _Pragma("unroll")                                       \
            for (int j = 0; j < 2; ++j)                             \
                acc[i][j] = __builtin_amdgcn_mfma_f32_16x16x32_bf16(af1[i], bg1[j], acc[i][j], 0, 0, 0); \
    } while (0)

#define LDSFENCE() asm volatile("s_waitcnt lgkmcnt(0)" ::: "memory")

    // prologue: tiles 0,1 -> regs; store tile 0 (set1 loads stay in flight)
    LOADS0(0);
    LOADS1(1);
    STORE0(0);            // compiler waits set0's vmcnt precisely
    LDSFENCE();
    __builtin_amdgcn_s_barrier();

    // steady state: 15 pairs cover tiles 0..29.
    // Pair invariant: buf0 = tile 2p ready; set1 = tile 2p+1 in flight.
#pragma unroll 1
    for (int p = 0; p < 15; ++p) {
        int e = 2 * p;
        // even: compute tile e (buf0); load e+2 -> set0; store e+1 -> buf1
        LOADS0(e + 2);
        STORE1(1);        // waits set1 only (set0 stays in flight)
        READF(0);
        MFMAS();
        LDSFENCE();
        __builtin_amdgcn_s_barrier();
        // odd: compute tile e+1 (buf1); load e+3 -> set1; store e+2 -> buf0
        LOADS1(e + 3);
        STORE0(0);        // waits set0 only
        READF(1);
        MFMAS();
        LDSFENCE();
        __builtin_amdgcn_s_barrier();
    }
    // tail: buf0 = tile 30 ready; set1 = tile 31 in flight
    STORE1(1);
    READF(0);
    MFMAS();
    LDSFENCE();
    __builtin_amdgcn_s_barrier();
    READF(1);
    MFMAS();

#undef LOADS0
#undef LOADS1
#undef STORE0
#undef STORE1
#undef READF
#undef MFMAS
#undef LDSFENCE

    // ---- fused epilogue: h = sigmoid(acc + b1); pt[j][t] = sum_m h*W2d[m][t]
    // C/D layout: col(n) = lane&15, row(m) = (lane>>4)*4 + reg  [m89-verified]
    float pt[2][NTGT];
#pragma unroll
    for (int j = 0; j < 2; ++j)
#pragma unroll
        for (int t = 0; t < NTGT; ++t) pt[j][t] = 0.f;

#pragma unroll
    for (int i = 0; i < 4; ++i) {
#pragma unroll
        for (int r = 0; r < 4; ++r) {
            int ml = wm * 64 + i * 16 + lg * 4 + r;
            float bn = s_b1[ml];
#pragma unroll
            for (int j = 0; j < 2; ++j) {
                float h = 1.f / (1.f + __expf(-(acc[i][j][r] + bn)));
#pragma unroll
                for (int t = 0; t < NTGT; ++t)
                    pt[j][t] += h * s_w2[ml][t];
            }
        }
    }
    // reduce over lg (lanes lr+16*lg share the same n column)
#pragma unroll
    for (int j = 0; j < 2; ++j)
#pragma unroll
        for (int t = 0; t < NTGT; ++t) {
            float val = pt[j][t];
            val += __shfl_xor(val, 16, 64);
            val += __shfl_xor(val, 32, 64);
            pt[j][t] = val;
        }
    if (lg == 0) {
#pragma unroll
        for (int j = 0; j < 2; ++j) {
            int nl = wn * 32 + j * 16 + lr;
#pragma unroll
            for (int t = 0; t < NTGT; ++t)
                s_pt[wm][nl][t] = pt[j][t];
        }
    }
    __syncthreads();
    // atomic add 64 n x 8 t into out (pre-filled with b2); coalesced by tid
    for (int idx = tid; idx < BN * NTGT; idx += 256) {
        int nl = idx >> 3, t = idx & 7;
        atomicAdd(&out[(size_t)(n0 + nl) * NTGT + t], s_pt[0][nl][t] + s_pt[1][nl][t]);
    }
}

extern "C" void kernel_launch(void* const* d_in, const int* in_sizes, int n_in,
                              void* d_out, int out_size, void* d_ws, size_t ws_size,
                              hipStream_t stream) {
    (void)in_sizes; (void)n_in; (void)out_size; (void)ws_size;
    const float* x   = (const float*)d_in[0];
    const float* w1  = (const float*)d_in[1];
    const float* b1  = (const float*)d_in[2];
    const float* w2  = (const float*)d_in[3];
    const float* b2  = (const float*)d_in[4];
    const int*   c1o = (const int*)d_in[5];
    const int*   c1i = (const int*)d_in[6];
    const int*   c2o = (const int*)d_in[7];
    const int*   c2i = (const int*)d_in[8];
    float* out = (float*)d_out;

    char* ws = (char*)d_ws;
    float*          W1f  = (float*)(ws + OFF_W1F);
    float*          W2d  = (float*)(ws + OFF_W2D);
    unsigned short* W1b  = (unsigned short*)(ws + OFF_W1B);

    // zero W1f+W2d, pre-fill out with b2
    k_zero<<<(ZERO_FLOAT4 + OUT_FLOAT4 + 255) / 256, 256, 0, stream>>>(
        (float4*)ws, (float4*)out, b2);

    // dense weight build
    k_build<<<(NNZ1 + NNZ2) / 256, 256, 0, stream>>>(w1, c1o, c1i, w2, c2o, c2i, W1f, W2d);

    // fp32 -> bf16 for W1 only (x converted in-register inside k_gemm)
    k_convert<<<NNEUR * NFEAT / 4 / 256, 256, 0, stream>>>(W1f, W1b);

    // layer 1 GEMM + bias + sigmoid + layer-2 (atomic) all fused
    k_gemm<<<(NNEUR / BM) * (BATCH / BN), 256, 0, stream>>>(W1b, x, b1, W2d, out);
}